// Round 2
// baseline (329.006 us; speedup 1.0000x reference)
//
#include <hip/hip_runtime.h>

// Problem constants
#define MQ 8        // codebooks
#define KQ 4096     // codes per codebook
#define DG 64       // dims per group (D/M)
#define NN 32       // batch
#define HW 4096     // 64*64 spatial
#define DD 512      // output channels

typedef float f32x4 __attribute__((ext_vector_type(4)));

// ---------------------------------------------------------------------------
// Kernel 1: v[m,k,c] = sum_d codebook[m,k,d] * wv[m,c,d]   (verified, ~6 us)
// ---------------------------------------------------------------------------
__global__ __launch_bounds__(256) void compute_v_kernel(
    const float* __restrict__ codebook,
    const float* __restrict__ wv,
    float* __restrict__ v) {
  __shared__ float wv_t[DG][DG + 1];   // [d][c]
  __shared__ float cb[64][DG];         // [k_local][d]

  const int m = blockIdx.y;
  const int k0 = blockIdx.x * 64;
  const int tid = threadIdx.x;

  const float4* wvm4 = (const float4*)(wv + (size_t)m * DG * DG);
  for (int i = tid; i < DG * DG / 4; i += 256) {
    int c = i >> 4, d4 = (i & 15) * 4;
    float4 val = wvm4[i];
    wv_t[d4 + 0][c] = val.x;
    wv_t[d4 + 1][c] = val.y;
    wv_t[d4 + 2][c] = val.z;
    wv_t[d4 + 3][c] = val.w;
  }
  const float4* cbm4 = (const float4*)(codebook + ((size_t)m * KQ + k0) * DG);
  float4* cb4 = (float4*)&cb[0][0];
  for (int i = tid; i < 64 * DG / 4; i += 256) cb4[i] = cbm4[i];
  __syncthreads();

  const int c = tid & 63;
  const int kq = tid >> 6;

  float acc[16];
#pragma unroll
  for (int kl = 0; kl < 16; ++kl) acc[kl] = 0.f;

  for (int d4 = 0; d4 < DG; d4 += 4) {
    float w0 = wv_t[d4 + 0][c];
    float w1 = wv_t[d4 + 1][c];
    float w2 = wv_t[d4 + 2][c];
    float w3 = wv_t[d4 + 3][c];
#pragma unroll
    for (int kl = 0; kl < 16; ++kl) {
      float4 cbv = *(const float4*)&cb[kq * 16 + kl][d4];  // broadcast b128
      acc[kl] += cbv.x * w0 + cbv.y * w1 + cbv.z * w2 + cbv.w * w3;
    }
  }

  float* vout = v + ((size_t)m * KQ + k0) * DG;
#pragma unroll
  for (int kl = 0; kl < 16; ++kl) {
    vout[(size_t)(kq * 16 + kl) * DG + c] = acc[kl];
  }
}

// ---------------------------------------------------------------------------
// Kernel 2: LDS-LUT gather.
// Block = (m, c-quad cq in 0..15, n-group of 8).  512 threads.
// GRID = MQ * 16 * (NN/8) = 512 blocks  (exactly 2 blocks/CU at 64 KB LDS,
// 16 waves/CU).  [Round-1 bug: grid was 256 -> n=16..31 never written.]
//   Stage once:  lut[k] = v[m][k][cq*4 .. cq*4+3]   (4096 x 16 B = 64 KB,
//                consecutive lanes -> consecutive 16 B chunks: conflict-free
//                b128 writes; v[m] (1 MB) stays L2-resident via m = b&7).
//   Main loop (no barriers): per n, lane l owns hw 4l..4l+3 of each 256-chunk:
//     4 scalar code loads (stride 32 B, L2-hot)
//     4 ds_read_b128 lut[r]      (4 c's per read -> 1/4 LDS instr per element)
//     4x4 in-register transpose
//     4 nontemporal dwordx4 stores -> 16 B/lane, 1 KB/instr, contiguous runs.
// Per element: 1/4 b128 read + 1/4 dwordx4 store; zero per-element LDS writes.
// Staging:output ratio = 64 KB : 512 KB per block.
// ---------------------------------------------------------------------------
__global__ __launch_bounds__(512, 4) void gather_lut_kernel(
    const int* __restrict__ codes,
    const float* __restrict__ v,
    float* __restrict__ out) {
  __shared__ f32x4 lut[KQ];            // 64 KB

  const int b = blockIdx.x;
  const int m = b & 7;                 // round-robin XCD heuristic
  const int rest = b >> 3;
  const int cq = rest & 15;            // c-quad 0..15
  const int n0 = (rest >> 4) * 8;      // n-group 0..3 -> n0 in {0,8,16,24}

  const int tid = threadIdx.x;
  const int w = tid >> 6;              // wave 0..7
  const int l = tid & 63;              // lane

  // ---- stage LUT ----
  const float* vm = v + (size_t)m * KQ * DG + cq * 4;
#pragma unroll
  for (int i = 0; i < 8; ++i) {
    int k = i * 512 + tid;
    lut[k] = *(const f32x4*)(vm + (size_t)k * DG);
  }
  __syncthreads();

  // ---- gather: 8 n, 2 chunks of 256 hw per wave ----
  for (int i = 0; i < 8; ++i) {
    const int n = n0 + i;
    const int* cp = codes + (size_t)n * HW * MQ + m;
    float* ob = out + ((size_t)n * DD + m * DG + cq * 4) * HW;

    int rr[8];
#pragma unroll
    for (int q = 0; q < 2; ++q) {
      const int hwb = (w * 2 + q) * 256 + 4 * l;
#pragma unroll
      for (int t = 0; t < 4; ++t) rr[q * 4 + t] = cp[(size_t)(hwb + t) * MQ];
    }

#pragma unroll
    for (int q = 0; q < 2; ++q) {
      const int hwb = (w * 2 + q) * 256 + 4 * l;
      f32x4 v0 = lut[rr[q * 4 + 0]];
      f32x4 v1 = lut[rr[q * 4 + 1]];
      f32x4 v2 = lut[rr[q * 4 + 2]];
      f32x4 v3 = lut[rr[q * 4 + 3]];
      f32x4 o0 = {v0.x, v1.x, v2.x, v3.x};
      f32x4 o1 = {v0.y, v1.y, v2.y, v3.y};
      f32x4 o2 = {v0.z, v1.z, v2.z, v3.z};
      f32x4 o3 = {v0.w, v1.w, v2.w, v3.w};
      __builtin_nontemporal_store(o0, (f32x4*)(ob + 0 * HW + hwb));
      __builtin_nontemporal_store(o1, (f32x4*)(ob + 1 * HW + hwb));
      __builtin_nontemporal_store(o2, (f32x4*)(ob + 2 * HW + hwb));
      __builtin_nontemporal_store(o3, (f32x4*)(ob + 3 * HW + hwb));
    }
  }
}

extern "C" void kernel_launch(void* const* d_in, const int* in_sizes, int n_in,
                              void* d_out, int out_size, void* d_ws, size_t ws_size,
                              hipStream_t stream) {
  const int* codes = (const int*)d_in[0];        // (32,64,64,8) int32
  const float* codebook = (const float*)d_in[1]; // (8,4096,64) f32
  const float* wv = (const float*)d_in[2];       // (8,64,64) f32
  float* out = (float*)d_out;                    // (32,512,64,64) f32
  float* v = (float*)d_ws;                       // 8*4096*64 f32 = 8 MB scratch

  compute_v_kernel<<<dim3(64, 8), 256, 0, stream>>>(codebook, wv, v);
  gather_lut_kernel<<<MQ * 16 * (NN / 8), 512, 0, stream>>>(codes, v, out);
}

// Round 3
// 320.941 us; speedup vs baseline: 1.0251x; 1.0251x over previous
//
#include <hip/hip_runtime.h>

// Problem constants
#define MQ 8        // codebooks
#define KQ 4096     // codes per codebook
#define DG 64       // dims per group (D/M)
#define NN 32       // batch
#define HW 4096     // 64*64 spatial
#define DD 512      // output channels

typedef float f32x4 __attribute__((ext_vector_type(4)));

// ---------------------------------------------------------------------------
// Kernel 1: v[m,k,c] = sum_d codebook[m,k,d] * wv[m,c,d]
// Output layout changed to quad-planes for kernel 2's coalesced staging:
//   v_q[m][cq][k][cc]  (cq = c>>2, cc = c&3), i.e. plane (m,cq) is a
//   contiguous 64 KB array of f32x4 over k.  Per-thread stores are 16
//   consecutive k at stride 16 B -> each 4-lane (cc 0..3) cluster fills
//   256 B contiguous; L2 merges to full lines.  8 MB total, trivial.
// ---------------------------------------------------------------------------
__global__ __launch_bounds__(256) void compute_v_kernel(
    const float* __restrict__ codebook,
    const float* __restrict__ wv,
    float* __restrict__ v) {
  __shared__ float wv_t[DG][DG + 1];   // [d][c]
  __shared__ float cb[64][DG];         // [k_local][d]

  const int m = blockIdx.y;
  const int k0 = blockIdx.x * 64;
  const int tid = threadIdx.x;

  const float4* wvm4 = (const float4*)(wv + (size_t)m * DG * DG);
  for (int i = tid; i < DG * DG / 4; i += 256) {
    int c = i >> 4, d4 = (i & 15) * 4;
    float4 val = wvm4[i];
    wv_t[d4 + 0][c] = val.x;
    wv_t[d4 + 1][c] = val.y;
    wv_t[d4 + 2][c] = val.z;
    wv_t[d4 + 3][c] = val.w;
  }
  const float4* cbm4 = (const float4*)(codebook + ((size_t)m * KQ + k0) * DG);
  float4* cb4 = (float4*)&cb[0][0];
  for (int i = tid; i < 64 * DG / 4; i += 256) cb4[i] = cbm4[i];
  __syncthreads();

  const int c = tid & 63;
  const int kq = tid >> 6;

  float acc[16];
#pragma unroll
  for (int kl = 0; kl < 16; ++kl) acc[kl] = 0.f;

  for (int d4 = 0; d4 < DG; d4 += 4) {
    float w0 = wv_t[d4 + 0][c];
    float w1 = wv_t[d4 + 1][c];
    float w2 = wv_t[d4 + 2][c];
    float w3 = wv_t[d4 + 3][c];
#pragma unroll
    for (int kl = 0; kl < 16; ++kl) {
      float4 cbv = *(const float4*)&cb[kq * 16 + kl][d4];  // broadcast b128
      acc[kl] += cbv.x * w0 + cbv.y * w1 + cbv.z * w2 + cbv.w * w3;
    }
  }

  // quad-plane store: v_q[m][c>>2][k][c&3]
  float* vout = v + ((size_t)(m * 16 + (c >> 2)) * KQ) * 4 + (c & 3);
#pragma unroll
  for (int kl = 0; kl < 16; ++kl) {
    vout[(size_t)(k0 + kq * 16 + kl) * 4] = acc[kl];
  }
}

// ---------------------------------------------------------------------------
// Kernel 2: LDS-LUT gather, round 3.
// Block = (m, cq 0..15, n-group of 4).  512 threads, grid 1024
// (2 blocks/CU at 64 KB LDS, 16 waves/CU, 2 dispatch rounds for overlap).
// Round-2 postmortem fixes:
//   * codes loads hoisted out of the main loop into 32 registers (issued
//     before staging -> latency hidden under the 64 KB LUT copy + barrier);
//     main loop has ZERO global reads and ZERO barriers.
//   * LUT staging is now a contiguous 64 KB block copy (v_q quad-plane
//     layout from kernel 1): lane i reads f32x4 at base+16i -> perfect
//     coalescing (round 2 had 256 B-strided 16 B reads = 1 line/lane).
// Main loop per n (4): per q (2): 4 ds_read_b128 lut[r] (random r: ~1.3x
// bank cost), 4x4 in-register transpose, 4 nontemporal dwordx4 stores
// (1 KB/instr contiguous; q=0,1 adjacent -> 2 KB runs per c-stream).
// m = b&7 keeps each m's v_q (1 MB) + codes lines in one XCD's L2.
// ---------------------------------------------------------------------------
__global__ __launch_bounds__(512, 4) void gather_lut_kernel(
    const int* __restrict__ codes,
    const float* __restrict__ v,
    float* __restrict__ out) {
  __shared__ f32x4 lut[KQ];            // 64 KB

  const int b = blockIdx.x;
  const int m = b & 7;                 // round-robin XCD heuristic
  const int rest = b >> 3;
  const int cq = rest & 15;            // c-quad 0..15
  const int n0 = (rest >> 4) * 4;      // n-group 0..7 -> n0 in {0,4,...,28}

  const int tid = threadIdx.x;
  const int w = tid >> 6;              // wave 0..7
  const int l = tid & 63;              // lane

  // ---- prefetch all codes for this block into registers (32 loads) ----
  int rr[32];
#pragma unroll
  for (int i = 0; i < 4; ++i) {
    const int* cp = codes + (size_t)(n0 + i) * HW * MQ + m;
#pragma unroll
    for (int q = 0; q < 2; ++q) {
      const int hwb = (w * 2 + q) * 256 + 4 * l;
#pragma unroll
      for (int t = 0; t < 4; ++t)
        rr[i * 8 + q * 4 + t] = cp[(size_t)(hwb + t) * MQ];
    }
  }

  // ---- stage LUT: contiguous 64 KB copy of quad-plane (m,cq) ----
  const f32x4* vq = (const f32x4*)(v + (size_t)(m * 16 + cq) * KQ * 4);
#pragma unroll
  for (int i = 0; i < 8; ++i) {
    int k = i * 512 + tid;
    lut[k] = vq[k];
  }
  __syncthreads();

  // ---- gather: no global reads, no barriers ----
#pragma unroll
  for (int i = 0; i < 4; ++i) {
    float* ob = out + ((size_t)(n0 + i) * DD + m * DG + cq * 4) * HW;
#pragma unroll
    for (int q = 0; q < 2; ++q) {
      const int hwb = (w * 2 + q) * 256 + 4 * l;
      f32x4 v0 = lut[rr[i * 8 + q * 4 + 0]];
      f32x4 v1 = lut[rr[i * 8 + q * 4 + 1]];
      f32x4 v2 = lut[rr[i * 8 + q * 4 + 2]];
      f32x4 v3 = lut[rr[i * 8 + q * 4 + 3]];
      f32x4 o0 = {v0.x, v1.x, v2.x, v3.x};
      f32x4 o1 = {v0.y, v1.y, v2.y, v3.y};
      f32x4 o2 = {v0.z, v1.z, v2.z, v3.z};
      f32x4 o3 = {v0.w, v1.w, v2.w, v3.w};
      __builtin_nontemporal_store(o0, (f32x4*)(ob + 0 * HW + hwb));
      __builtin_nontemporal_store(o1, (f32x4*)(ob + 1 * HW + hwb));
      __builtin_nontemporal_store(o2, (f32x4*)(ob + 2 * HW + hwb));
      __builtin_nontemporal_store(o3, (f32x4*)(ob + 3 * HW + hwb));
    }
  }
}

extern "C" void kernel_launch(void* const* d_in, const int* in_sizes, int n_in,
                              void* d_out, int out_size, void* d_ws, size_t ws_size,
                              hipStream_t stream) {
  const int* codes = (const int*)d_in[0];        // (32,64,64,8) int32
  const float* codebook = (const float*)d_in[1]; // (8,4096,64) f32
  const float* wv = (const float*)d_in[2];       // (8,64,64) f32
  float* out = (float*)d_out;                    // (32,512,64,64) f32
  float* v = (float*)d_ws;                       // 8 MB scratch (quad-plane v_q)

  compute_v_kernel<<<dim3(64, 8), 256, 0, stream>>>(codebook, wv, v);
  gather_lut_kernel<<<MQ * 16 * (NN / 4), 512, 0, stream>>>(codes, v, out);
}

// Round 4
// 305.411 us; speedup vs baseline: 1.0773x; 1.0508x over previous
//
#include <hip/hip_runtime.h>

// Problem constants
#define MQ 8        // codebooks
#define KQ 4096     // codes per codebook
#define DG 64       // dims per group (D/M)
#define NN 32       // batch
#define HW 4096     // 64*64 spatial
#define DD 512      // output channels

typedef float f32x4 __attribute__((ext_vector_type(4)));

// ---------------------------------------------------------------------------
// Kernel 1: v[m,k,c] = sum_d codebook[m,k,d] * wv[m,c,d]
// Quad-plane output layout (verified round 3):
//   v_q[m][cq][k][cc]  (cq = c>>2, cc = c&3); plane (m,cq) = contiguous
//   64 KB f32x4 array over k.
// ---------------------------------------------------------------------------
__global__ __launch_bounds__(256) void compute_v_kernel(
    const float* __restrict__ codebook,
    const float* __restrict__ wv,
    float* __restrict__ v) {
  __shared__ float wv_t[DG][DG + 1];   // [d][c]
  __shared__ float cb[64][DG];         // [k_local][d]

  const int m = blockIdx.y;
  const int k0 = blockIdx.x * 64;
  const int tid = threadIdx.x;

  const float4* wvm4 = (const float4*)(wv + (size_t)m * DG * DG);
  for (int i = tid; i < DG * DG / 4; i += 256) {
    int c = i >> 4, d4 = (i & 15) * 4;
    float4 val = wvm4[i];
    wv_t[d4 + 0][c] = val.x;
    wv_t[d4 + 1][c] = val.y;
    wv_t[d4 + 2][c] = val.z;
    wv_t[d4 + 3][c] = val.w;
  }
  const float4* cbm4 = (const float4*)(codebook + ((size_t)m * KQ + k0) * DG);
  float4* cb4 = (float4*)&cb[0][0];
  for (int i = tid; i < 64 * DG / 4; i += 256) cb4[i] = cbm4[i];
  __syncthreads();

  const int c = tid & 63;
  const int kq = tid >> 6;

  float acc[16];
#pragma unroll
  for (int kl = 0; kl < 16; ++kl) acc[kl] = 0.f;

  for (int d4 = 0; d4 < DG; d4 += 4) {
    float w0 = wv_t[d4 + 0][c];
    float w1 = wv_t[d4 + 1][c];
    float w2 = wv_t[d4 + 2][c];
    float w3 = wv_t[d4 + 3][c];
#pragma unroll
    for (int kl = 0; kl < 16; ++kl) {
      float4 cbv = *(const float4*)&cb[kq * 16 + kl][d4];  // broadcast b128
      acc[kl] += cbv.x * w0 + cbv.y * w1 + cbv.z * w2 + cbv.w * w3;
    }
  }

  // quad-plane store: v_q[m][c>>2][k][c&3]
  float* vout = v + ((size_t)(m * 16 + (c >> 2)) * KQ) * 4 + (c & 3);
#pragma unroll
  for (int kl = 0; kl < 16; ++kl) {
    vout[(size_t)(k0 + kq * 16 + kl) * 4] = acc[kl];
  }
}

// ---------------------------------------------------------------------------
// Kernel 2 (round 4): direct register gather — NO LDS, NO barriers.
// Round-3 postmortem: LDS-LUT was the wrong home for random 16 B gathers —
// the single per-CU LDS pipe serializes random-bank b128 reads and the
// 128-VGPR cap spilled rr[]; L2 handles random 16 B gathers with far more
// parallelism (tile kernel proved this).  So: gather straight from the
// XCD-pinned L2-resident v_q plane into registers, transpose, wide stores.
//
// Block = (n, hw-chunk of 1024, m).  256 threads, grid 1024 (4 blocks/CU,
// 16 waves/CU at <=128 VGPR).  Lane owns hw0..hw0+3:
//   4 scalar code loads  (all 4 land in ONE 128-B line: line = 4 hw x 8 m)
//   per cq (16): 4 global b128 loads from v_q[m][cq] (random within 1 MB,
//                L2-resident via m = b&7 XCD round-robin),
//                4x4 in-register transpose,
//                4 NT dwordx4 stores -> 1 KB contiguous per wave-instr.
// Per element: 1/4 b128 load + 1/4 b128 store + ~1 VALU.  Zero LDS traffic.
// ---------------------------------------------------------------------------
__global__ __launch_bounds__(256, 4) void gather_direct_kernel(
    const int* __restrict__ codes,
    const float* __restrict__ v,
    float* __restrict__ out) {
  const int b = blockIdx.x;
  const int m = b & 7;                 // XCD round-robin: v_q[m] stays in one L2
  const int chunk = (b >> 3) & 3;      // hw chunk of 1024
  const int n = b >> 5;                // 0..31

  const int tid = threadIdx.x;
  const int hw0 = chunk * 1024 + 4 * tid;   // this thread's 4 hw

  // 4 code loads — same 128-B line, L1/L2 hot across m-blocks
  const int* cp = codes + ((size_t)n * HW + hw0) * MQ + m;
  const int r0 = cp[0 * MQ];
  const int r1 = cp[1 * MQ];
  const int r2 = cp[2 * MQ];
  const int r3 = cp[3 * MQ];

  const f32x4* vq = (const f32x4*)v + (size_t)m * 16 * KQ;
  float* ob = out + ((size_t)n * DD + m * DG) * HW + hw0;

#pragma unroll
  for (int cq = 0; cq < 16; ++cq) {
    const f32x4* plane = vq + (size_t)cq * KQ;
    f32x4 v0 = plane[r0];
    f32x4 v1 = plane[r1];
    f32x4 v2 = plane[r2];
    f32x4 v3 = plane[r3];
    f32x4 o0 = {v0.x, v1.x, v2.x, v3.x};
    f32x4 o1 = {v0.y, v1.y, v2.y, v3.y};
    f32x4 o2 = {v0.z, v1.z, v2.z, v3.z};
    f32x4 o3 = {v0.w, v1.w, v2.w, v3.w};
    float* oc = ob + (size_t)(cq * 4) * HW;
    __builtin_nontemporal_store(o0, (f32x4*)(oc + 0 * HW));
    __builtin_nontemporal_store(o1, (f32x4*)(oc + 1 * HW));
    __builtin_nontemporal_store(o2, (f32x4*)(oc + 2 * HW));
    __builtin_nontemporal_store(o3, (f32x4*)(oc + 3 * HW));
  }
}

extern "C" void kernel_launch(void* const* d_in, const int* in_sizes, int n_in,
                              void* d_out, int out_size, void* d_ws, size_t ws_size,
                              hipStream_t stream) {
  const int* codes = (const int*)d_in[0];        // (32,64,64,8) int32
  const float* codebook = (const float*)d_in[1]; // (8,4096,64) f32
  const float* wv = (const float*)d_in[2];       // (8,64,64) f32
  float* out = (float*)d_out;                    // (32,512,64,64) f32
  float* v = (float*)d_ws;                       // 8 MB scratch (quad-plane v_q)

  compute_v_kernel<<<dim3(64, 8), 256, 0, stream>>>(codebook, wv, v);
  gather_direct_kernel<<<NN * 4 * MQ, 256, 0, stream>>>(codes, v, out);
}

// Round 5
// 302.318 us; speedup vs baseline: 1.0883x; 1.0102x over previous
//
#include <hip/hip_runtime.h>

// Problem constants
#define MQ 8        // codebooks
#define KQ 4096     // codes per codebook
#define DG 64       // dims per group (D/M)
#define NN 32       // batch
#define HW 4096     // 64*64 spatial
#define DD 512      // output channels

typedef float f32x4 __attribute__((ext_vector_type(4)));

// ---------------------------------------------------------------------------
// Kernel 1: v[m,k,c] = sum_d codebook[m,k,d] * wv[m,c,d]
// Output layout (round 5): line-planes
//   v128[m][g2][k][c32]   (g2 = c>>5, c32 = c&31) — one k-row = 32 floats
//   = exactly one 128-B cache line.  Plane (m,g2) = 512 KB; total 8 MB.
// ---------------------------------------------------------------------------
__global__ __launch_bounds__(256) void compute_v_kernel(
    const float* __restrict__ codebook,
    const float* __restrict__ wv,
    float* __restrict__ v) {
  __shared__ float wv_t[DG][DG + 1];   // [d][c]
  __shared__ float cb[64][DG];         // [k_local][d]

  const int m = blockIdx.y;
  const int k0 = blockIdx.x * 64;
  const int tid = threadIdx.x;

  const float4* wvm4 = (const float4*)(wv + (size_t)m * DG * DG);
  for (int i = tid; i < DG * DG / 4; i += 256) {
    int c = i >> 4, d4 = (i & 15) * 4;
    float4 val = wvm4[i];
    wv_t[d4 + 0][c] = val.x;
    wv_t[d4 + 1][c] = val.y;
    wv_t[d4 + 2][c] = val.z;
    wv_t[d4 + 3][c] = val.w;
  }
  const float4* cbm4 = (const float4*)(codebook + ((size_t)m * KQ + k0) * DG);
  float4* cb4 = (float4*)&cb[0][0];
  for (int i = tid; i < 64 * DG / 4; i += 256) cb4[i] = cbm4[i];
  __syncthreads();

  const int c = tid & 63;
  const int kq = tid >> 6;

  float acc[16];
#pragma unroll
  for (int kl = 0; kl < 16; ++kl) acc[kl] = 0.f;

  for (int d4 = 0; d4 < DG; d4 += 4) {
    float w0 = wv_t[d4 + 0][c];
    float w1 = wv_t[d4 + 1][c];
    float w2 = wv_t[d4 + 2][c];
    float w3 = wv_t[d4 + 3][c];
#pragma unroll
    for (int kl = 0; kl < 16; ++kl) {
      float4 cbv = *(const float4*)&cb[kq * 16 + kl][d4];  // broadcast b128
      acc[kl] += cbv.x * w0 + cbv.y * w1 + cbv.z * w2 + cbv.w * w3;
    }
  }

  // line-plane store: v128[m][c>>5][k][c&31]
  float* vout = v + ((size_t)(m * 2 + (c >> 5)) * KQ) * 32 + (c & 31);
#pragma unroll
  for (int kl = 0; kl < 16; ++kl) {
    vout[(size_t)(k0 + kq * 16 + kl) * 32] = acc[kl];
  }
}

// ---------------------------------------------------------------------------
// Kernel 2 (round 5): oct-coalesced direct gather — no LDS, no barriers.
// Round-4 postmortem: per-lane random 16-B loads -> 64 unique sectors per
// wave-load instr, TA/L2 request-rate bound (~27 us of serialized address
// processing).  Fix: 8 lanes (an oct) share one code row; v rows are full
// 128-B lines (v128 layout), lane lo=l&7 loads chunk lo -> every wave-load
// = 8 unique FULLY-covered lines (8x fewer requests, same bytes).
//
// Block = (n, hw-chunk of 1024, m).  256 threads, grid 1024.  Per pass
// (128 hw per block-wave set, 8 passes):
//   oct o (=l>>3) owns hw q0..q0+3; 4 scalar code loads (one line, shared)
//   per g2 (2): 4 coalesced line loads (t=0..3) -> lane holds 4hw x 4c,
//               in-register 4x4 transpose,
//               4 NT dwordx4 stores: 8 c-streams x 128 B contiguous/instr.
// Per element: 1/4 b128 load + 1/4 b128 store; all wave mem-instrs = 8 lines.
// m = b&7 keeps v128[m] (1 MB) + codes (4 MB total) L2-resident per XCD.
// ---------------------------------------------------------------------------
__global__ __launch_bounds__(256, 4) void gather_oct_kernel(
    const int* __restrict__ codes,
    const float* __restrict__ v,
    float* __restrict__ out) {
  const int b = blockIdx.x;
  const int m = b & 7;                 // XCD round-robin
  const int chunk = (b >> 3) & 3;      // hw chunk of 1024
  const int n = b >> 5;                // 0..31

  const int tid = threadIdx.x;
  const int w = tid >> 6;              // wave 0..3
  const int l = tid & 63;              // lane
  const int oc8 = l >> 3;              // oct 0..7 (hw group)
  const int lo = l & 7;                // lane-in-oct (16-B chunk of row)

  const float* vm = v + (size_t)m * 2 * KQ * 32;   // v128[m]
  const int* cp = codes + (size_t)n * HW * MQ + m;
  float* ob = out + ((size_t)n * DD + m * DG) * HW;

  for (int p = 0; p < 8; ++p) {
    const int hwq = chunk * 1024 + p * 128 + w * 32 + oc8 * 4;  // oct's 4 hw
    int r[4];
#pragma unroll
    for (int t = 0; t < 4; ++t) r[t] = cp[(size_t)(hwq + t) * MQ];

#pragma unroll
    for (int g = 0; g < 2; ++g) {
      const float* plane = vm + (size_t)g * KQ * 32;
      f32x4 v0 = *(const f32x4*)(plane + (size_t)r[0] * 32 + lo * 4);
      f32x4 v1 = *(const f32x4*)(plane + (size_t)r[1] * 32 + lo * 4);
      f32x4 v2 = *(const f32x4*)(plane + (size_t)r[2] * 32 + lo * 4);
      f32x4 v3 = *(const f32x4*)(plane + (size_t)r[3] * 32 + lo * 4);
      f32x4 o0 = {v0.x, v1.x, v2.x, v3.x};
      f32x4 o1 = {v0.y, v1.y, v2.y, v3.y};
      f32x4 o2 = {v0.z, v1.z, v2.z, v3.z};
      f32x4 o3 = {v0.w, v1.w, v2.w, v3.w};
      // c = g*32 + lo*4 + e ; hw = hwq..hwq+3
      float* oc = ob + (size_t)(g * 32 + lo * 4) * HW + hwq;
      __builtin_nontemporal_store(o0, (f32x4*)(oc + 0 * HW));
      __builtin_nontemporal_store(o1, (f32x4*)(oc + 1 * HW));
      __builtin_nontemporal_store(o2, (f32x4*)(oc + 2 * HW));
      __builtin_nontemporal_store(o3, (f32x4*)(oc + 3 * HW));
    }
  }
}

extern "C" void kernel_launch(void* const* d_in, const int* in_sizes, int n_in,
                              void* d_out, int out_size, void* d_ws, size_t ws_size,
                              hipStream_t stream) {
  const int* codes = (const int*)d_in[0];        // (32,64,64,8) int32
  const float* codebook = (const float*)d_in[1]; // (8,4096,64) f32
  const float* wv = (const float*)d_in[2];       // (8,64,64) f32
  float* out = (float*)d_out;                    // (32,512,64,64) f32
  float* v = (float*)d_ws;                       // 8 MB scratch (line-plane v128)

  compute_v_kernel<<<dim3(64, 8), 256, 0, stream>>>(codebook, wv, v);
  gather_oct_kernel<<<NN * 4 * MQ, 256, 0, stream>>>(codes, v, out);
}